// Round 1
// 255.670 us; speedup vs baseline: 1.2181x; 1.2181x over previous
//
#include <hip/hip_runtime.h>

#define HSZ 50        // real hidden units
#define TSZ 512       // timesteps
#define NB  8         // batches per workgroup -> 256 wgs (1 per CU)
#define KPAD 72       // hlds row stride in f16 (144 B, 16B-aligned)

typedef _Float16 half8  __attribute__((ext_vector_type(8)));
typedef _Float16 half2v __attribute__((ext_vector_type(2)));
typedef float   floatx4 __attribute__((ext_vector_type(4)));

// sigmoid/tanh via exp+rcp, robust at extremes (proven R4-R9, absmax ~1e-3)
__device__ __forceinline__ float fast_sig(float x) {
    return __builtin_amdgcn_rcpf(1.0f + __expf(-x));
}
__device__ __forceinline__ float fast_tanh(float x) {
    return fmaf(-2.0f, __builtin_amdgcn_rcpf(1.0f + __expf(2.0f * x)), 1.0f);
}
// lane ^= 8 crossbar move (BitMode: xor=8 -> (8<<10)|0x1F)
__device__ __forceinline__ float swz8(float v) {
    return __int_as_float(__builtin_amdgcn_ds_swizzle(__float_as_int(v), 0x201F));
}

// R10: latency-chain surgery on the R9 K-augmented skeleton.
// (1) gl repack round-trip (4x ds_write_b128 + lgkmcnt(0) + ds_read_b128)
//     replaced by in-register redistribution: lanes n>=8 (idle MFMA columns)
//     take their n-8 partner's acc[g][2..3] via 8x ds_swizzle(lane^8).
//     Each lane then owns 2 (unit,batch) pairs: lo lanes units 4q..4q+1,
//     hi lanes units 4q+2..4q+3, batch n&7. h-write is one b32 (2 f16).
// (2) NB=8 -> 256 wgs = 1 per CU: removes co-resident-wg LDS contention and
//     barrier skew; halves total MFMA count (8 of 16 B-columns real).
// (3) Aug slots k=50 (1.0) / k=51 (x_{t+1}) are exactly units 50,51 =
//     wave 3, q=0, hi lanes -> folded into their h-write (no extra store).
__global__ __launch_bounds__(256)
void lstm_swz(const float* __restrict__ x,
              const float* __restrict__ W_ih,
              const float* __restrict__ W_hh,
              const float* __restrict__ b_ih,
              const float* __restrict__ b_hh,
              const float* __restrict__ W_lin,
              const float* __restrict__ b_lin,
              float* __restrict__ out)
{
    __shared__ float xs[TSZ][NB];                         // x^T [t][n]  (16 KB)
    __shared__ __align__(16) _Float16 hlds[2][16][KPAD];  // aug-h^T dbuf (4.5 KB)

    const int tid = threadIdx.x;
    const int w   = tid >> 6;        // wave id 0..3 -> unit group [16w,16w+16)
    const int ln  = tid & 63;        // lane
    const int n   = ln & 15;         // MFMA column
    const int q   = ln >> 4;         // quad
    const int hi  = (n >> 3) & 1;    // 0: own units 4q..4q+1, 1: partner's 4q+2..3
    const int nb  = n & 7;           // real batch this lane activates
    const int b0  = blockIdx.x * NB;

    // --- stage x transposed: global [b][t] -> LDS [t][b] (coalesced) ---
    const float* xg = x + (size_t)b0 * TSZ;
    for (int i = tid; i < NB * TSZ; i += 256)
        xs[i & (TSZ - 1)][i >> 9] = xg[i];
    // --- init h buffers: zero except k==50 slot = 1.0 (both buffers) ---
    for (int i = tid; i < 2 * 16 * KPAD; i += 256)
        ((_Float16*)hlds)[i] = (i % KPAD == 50) ? (_Float16)1.0f : (_Float16)0.0f;

    // --- A fragments: lane holds A[m=16w+n][k=kt*32+q*8+j], augmented:
    //     k<50 -> W_hh ; k==50 -> b_ih+b_hh ; k==51 -> W_ih ; else 0.
    const int uA = 16 * w + n;
    half8 af[4][2];
#pragma unroll
    for (int g = 0; g < 4; ++g) {
        const int row = g * HSZ + uA;
        const bool rok = (uA < HSZ);
#pragma unroll
        for (int kt = 0; kt < 2; ++kt) {
#pragma unroll
            for (int j = 0; j < 8; ++j) {
                const int k = kt * 32 + q * 8 + j;
                float v = 0.0f;
                if (rok) {
                    if (k < HSZ)      v = W_hh[row * HSZ + k];
                    else if (k == 50) v = b_ih[row] + b_hh[row];
                    else if (k == 51) v = W_ih[row];
                }
                af[g][kt][j] = (_Float16)v;
            }
        }
    }

    float c0 = 0.0f, c1 = 0.0f;      // lane-local cell states (2 units, batch nb)
    __syncthreads();                 // xs + hlds base fill ready
    if (tid < NB)                    // x_0 into buffer 0's aug slot
        hlds[0][tid][51] = (_Float16)xs[0][tid];
    __syncthreads();

    const floatx4 zero4 = {0.0f, 0.0f, 0.0f, 0.0f};
    // h destination: row nb, cols 16w+4q+2*hi .. +1 (covers all 64 units/wave)
    const int kcol = 16 * w + 4 * q + 2 * hi;
    _Float16* const hwp0 = &hlds[0][nb][kcol];
    _Float16* const hwp1 = &hlds[1][nb][kcol];
    const bool xlane = (w == 3) && (q == 0) && (hi == 1);  // units 50,51

#pragma unroll 2
    for (int t = 0; t < TSZ; ++t) {
        const int rb = t & 1, wb = rb ^ 1;

        // B fragments: hlds[rb][n][k-contiguous] (cols 8..15 are dummy batches)
        const half8 bf0 = *(const half8*)&hlds[rb][n][q * 8];
        const half8 bf1 = *(const half8*)&hlds[rb][n][32 + q * 8];

        // Next step's x (wave 3 only; consumed by xlane lanes at write time).
        float xnext = 0.0f;
        if (w == 3) xnext = xs[(t + 1) & (TSZ - 1)][ln & 7];

        floatx4 acc[4];
#pragma unroll
        for (int g = 0; g < 4; ++g) {
            acc[g] = __builtin_amdgcn_mfma_f32_16x16x32_f16(af[g][0], bf0, zero4,  0, 0, 0);
            acc[g] = __builtin_amdgcn_mfma_f32_16x16x32_f16(af[g][1], bf1, acc[g], 0, 0, 0);
        }

        // In-register redistribution: hi lanes take partner (n-8)'s r=2,3.
        // All lanes execute the swizzles (full exec); selection is cndmask.
        float pa[4], pb[4];
#pragma unroll
        for (int g = 0; g < 4; ++g) {
            const float s2 = swz8(acc[g][2]);
            const float s3 = swz8(acc[g][3]);
            pa[g] = hi ? s2 : acc[g][0];
            pb[g] = hi ? s3 : acc[g][1];
        }

        const float i0 = fast_sig (pa[0]);
        const float f0 = fast_sig (pa[1]);
        const float g0 = fast_tanh(pa[2]);
        const float o0 = fast_sig (pa[3]);
        const float i1 = fast_sig (pb[0]);
        const float f1 = fast_sig (pb[1]);
        const float g1 = fast_tanh(pb[2]);
        const float o1 = fast_sig (pb[3]);
        c0 = fmaf(f0, c0, i0 * g0);
        c1 = fmaf(f1, c1, i1 * g1);
        float h0 = o0 * fast_tanh(c0);
        float h1 = o1 * fast_tanh(c1);
        // pad units (rows >= 50 have zero A-rows) produce h==0: safe to write.
        // units 50,51 instead carry the augmentation {1.0, x_{t+1}}:
        if (xlane) { h0 = 1.0f; h1 = xnext; }

        _Float16* const hw = wb ? hwp1 : hwp0;
        *(half2v*)hw = half2v{(_Float16)h0, (_Float16)h1};
        __syncthreads();             // h(t) visible for next step's B-read
    }

    // --- epilogue: out[b0+n'] = b_lin + sum_u h_T[u]*W_lin[u]; TSZ even -> buf 0
    if (w == 0 && ln < NB) {
        float acc = b_lin[0];
        for (int u = 0; u < HSZ; ++u)
            acc = fmaf((float)hlds[0][ln][u], W_lin[u], acc);
        out[(size_t)b0 + ln] = acc;
    }
}

extern "C" void kernel_launch(void* const* d_in, const int* in_sizes, int n_in,
                              void* d_out, int out_size, void* d_ws, size_t ws_size,
                              hipStream_t stream) {
    const float* x     = (const float*)d_in[0];
    const float* W_ih  = (const float*)d_in[1];
    const float* W_hh  = (const float*)d_in[2];
    const float* b_ih  = (const float*)d_in[3];
    const float* b_hh  = (const float*)d_in[4];
    const float* W_lin = (const float*)d_in[5];
    const float* b_lin = (const float*)d_in[6];
    float* outp = (float*)d_out;

    const int B = in_sizes[0] / TSZ;   // 2048 -> 256 workgroups of 8 batches
    hipLaunchKernelGGL(lstm_swz, dim3(B / NB), dim3(256), 0, stream,
                       x, W_ih, W_hh, b_ih, b_hh, W_lin, b_lin, outp);
}

// Round 2
// 244.730 us; speedup vs baseline: 1.2725x; 1.0447x over previous
//
#include <hip/hip_runtime.h>

#define HSZ 50        // real hidden units
#define TSZ 512       // timesteps
#define NB  8         // batches per workgroup -> 256 wgs (1 per CU)
#define KPAD 72       // hlds row stride in f16 (144 B, 16B-aligned)

typedef _Float16 half8  __attribute__((ext_vector_type(8)));
typedef _Float16 half2v __attribute__((ext_vector_type(2)));
typedef float   floatx4 __attribute__((ext_vector_type(4)));

// Activations on pre-scaled arguments (A rows carry the log2e factors):
//   sigmoid gates: y = -log2e * x  ->  sig = rcp(1 + exp2(y))
//   tanh gate:     y = 2*log2e * x ->  tanh = 1 - 2*rcp(1 + exp2(y))
// Robust at extremes: exp2->inf => rcp->0 ; exp2->0 => rcp(1)=1.
__device__ __forceinline__ float sig_y(float y) {
    return __builtin_amdgcn_rcpf(1.0f + __builtin_amdgcn_exp2f(y));
}
__device__ __forceinline__ float tanh_y(float y) {
    return fmaf(-2.0f, __builtin_amdgcn_rcpf(1.0f + __builtin_amdgcn_exp2f(y)), 1.0f);
}

// R11: chain surgery on R10.
// (1) Mirror-columns: B cols 8..15 replicate batches 0..7 (h written to rows
//     nb and nb+8). Col n>=8 then computes the same gates as col n-8, so hi
//     lanes take acc[g][2..3] from their OWN registers -> the 8x ds_swizzle
//     LDS round trip (~140 cy on the chain) becomes 8 cndmasks (~16 cy).
//     Cost: one extra ds_write_b32 per lane, issued back-to-back (off-chain).
// (2) A-row pre-scaling: fold -log2e (i,f,o) / +2log2e (g) into the augmented
//     A fragments (weights, bias, W_ih). MFMA output is exp2-ready; deletes
//     one dependent VALU mul per activation chain.
// Kept from R10: K-augmentation (bias at k=50, x_t at k=51 -> zero C-input),
// NB=8 (1 wg/CU), 1 barrier/step, f16 h exchange.
__global__ __launch_bounds__(256)
void lstm_mir(const float* __restrict__ x,
              const float* __restrict__ W_ih,
              const float* __restrict__ W_hh,
              const float* __restrict__ b_ih,
              const float* __restrict__ b_hh,
              const float* __restrict__ W_lin,
              const float* __restrict__ b_lin,
              float* __restrict__ out)
{
    __shared__ float xs[TSZ][NB];                         // x^T [t][n]  (16 KB)
    __shared__ __align__(16) _Float16 hlds[2][16][KPAD];  // aug-h^T dbuf (4.5 KB)

    const int tid = threadIdx.x;
    const int w   = tid >> 6;        // wave id 0..3 -> unit group [16w,16w+16)
    const int ln  = tid & 63;        // lane
    const int n   = ln & 15;         // MFMA column
    const int q   = ln >> 4;         // quad
    const int hi  = (n >> 3) & 1;    // 0: units 4q..4q+1, 1: units 4q+2..4q+3
    const int nb  = n & 7;           // real batch this lane activates
    const int b0  = blockIdx.x * NB;

    // --- stage x transposed: global [b][t] -> LDS [t][b] (coalesced) ---
    const float* xg = x + (size_t)b0 * TSZ;
    for (int i = tid; i < NB * TSZ; i += 256)
        xs[i & (TSZ - 1)][i >> 9] = xg[i];
    // --- init h buffers: zero except k==50 slot = 1.0 (both buffers) ---
    for (int i = tid; i < 2 * 16 * KPAD; i += 256)
        ((_Float16*)hlds)[i] = (i % KPAD == 50) ? (_Float16)1.0f : (_Float16)0.0f;

    // --- A fragments: lane holds A[m=16w+n][k=kt*32+q*8+j], augmented and
    //     pre-scaled: k<50 -> W_hh ; k==50 -> b_ih+b_hh ; k==51 -> W_ih.
    //     Row scale: gates i,f,o -> -log2e ; gate g -> +2*log2e.
    const int uA = 16 * w + n;
    half8 af[4][2];
#pragma unroll
    for (int g = 0; g < 4; ++g) {
        const float gs = (g == 2) ? 2.88539008f : -1.44269504f;
        const int row = g * HSZ + uA;
        const bool rok = (uA < HSZ);
#pragma unroll
        for (int kt = 0; kt < 2; ++kt) {
#pragma unroll
            for (int j = 0; j < 8; ++j) {
                const int k = kt * 32 + q * 8 + j;
                float v = 0.0f;
                if (rok) {
                    if (k < HSZ)      v = W_hh[row * HSZ + k];
                    else if (k == 50) v = b_ih[row] + b_hh[row];
                    else if (k == 51) v = W_ih[row];
                }
                af[g][kt][j] = (_Float16)(v * gs);
            }
        }
    }

    float c0 = 0.0f, c1 = 0.0f;      // lane-local cell states (2 units, batch nb)
    __syncthreads();                 // xs + hlds base fill ready
    if (tid < 16)                    // x_0 into buffer 0's aug slot, both halves
        hlds[0][tid][51] = (_Float16)xs[0][tid & 7];
    __syncthreads();

    const floatx4 zero4 = {0.0f, 0.0f, 0.0f, 0.0f};
    // h destination: row nb (+ mirror nb+8), cols 16w+4q+2*hi .. +1
    const int kcol = 16 * w + 4 * q + 2 * hi;
    _Float16* const hwp0 = &hlds[0][nb][kcol];
    _Float16* const hwp1 = &hlds[1][nb][kcol];
    const bool xlane = (w == 3) && (q == 0) && (hi == 1);  // units 50,51

#pragma unroll 2
    for (int t = 0; t < TSZ; ++t) {
        const int rb = t & 1, wb = rb ^ 1;

        // B fragments: hlds[rb][n][k-contiguous]; cols 8..15 mirror cols 0..7
        const half8 bf0 = *(const half8*)&hlds[rb][n][q * 8];
        const half8 bf1 = *(const half8*)&hlds[rb][n][32 + q * 8];

        // Next step's x (wave 3 only; consumed by xlane lanes at write time).
        float xnext = 0.0f;
        if (w == 3) xnext = xs[(t + 1) & (TSZ - 1)][ln & 7];

        floatx4 acc[4];
#pragma unroll
        for (int g = 0; g < 4; ++g) {
            acc[g] = __builtin_amdgcn_mfma_f32_16x16x32_f16(af[g][0], bf0, zero4,  0, 0, 0);
            acc[g] = __builtin_amdgcn_mfma_f32_16x16x32_f16(af[g][1], bf1, acc[g], 0, 0, 0);
        }

        // In-register selection (mirror cols): hi lanes use their own r=2,3.
        float pa[4], pb[4];
#pragma unroll
        for (int g = 0; g < 4; ++g) {
            pa[g] = hi ? acc[g][2] : acc[g][0];
            pb[g] = hi ? acc[g][3] : acc[g][1];
        }

        const float i0 = sig_y (pa[0]);
        const float f0 = sig_y (pa[1]);
        const float g0 = tanh_y(pa[2]);
        const float o0 = sig_y (pa[3]);
        const float i1 = sig_y (pb[0]);
        const float f1 = sig_y (pb[1]);
        const float g1 = tanh_y(pb[2]);
        const float o1 = sig_y (pb[3]);
        c0 = fmaf(f0, c0, i0 * g0);
        c1 = fmaf(f1, c1, i1 * g1);
        float h0 = o0 * tanh_y(c0 * 2.88539008f);
        float h1 = o1 * tanh_y(c1 * 2.88539008f);
        // pad units (zero A-rows) produce h==0: safe to write.
        // units 50,51 instead carry the augmentation {1.0, x_{t+1}}:
        if (xlane) { h0 = 1.0f; h1 = xnext; }

        _Float16* const hw = wb ? hwp1 : hwp0;
        const half2v hv = {(_Float16)h0, (_Float16)h1};
        *(half2v*)hw = hv;                       // rows 0..7: real batches
        *(half2v*)(hw + 8 * KPAD) = hv;          // rows 8..15: mirror batches
        __syncthreads();             // h(t) visible for next step's B-read
    }

    // --- epilogue: out[b0+n'] = b_lin + sum_u h_T[u]*W_lin[u]; TSZ even -> buf 0
    if (w == 0 && ln < NB) {
        float acc = b_lin[0];
        for (int u = 0; u < HSZ; ++u)
            acc = fmaf((float)hlds[0][ln][u], W_lin[u], acc);
        out[(size_t)b0 + ln] = acc;
    }
}

extern "C" void kernel_launch(void* const* d_in, const int* in_sizes, int n_in,
                              void* d_out, int out_size, void* d_ws, size_t ws_size,
                              hipStream_t stream) {
    const float* x     = (const float*)d_in[0];
    const float* W_ih  = (const float*)d_in[1];
    const float* W_hh  = (const float*)d_in[2];
    const float* b_ih  = (const float*)d_in[3];
    const float* b_hh  = (const float*)d_in[4];
    const float* W_lin = (const float*)d_in[5];
    const float* b_lin = (const float*)d_in[6];
    float* outp = (float*)d_out;

    const int B = in_sizes[0] / TSZ;   // 2048 -> 256 workgroups of 8 batches
    hipLaunchKernelGGL(lstm_mir, dim3(B / NB), dim3(256), 0, stream,
                       x, W_ih, W_hh, b_ih, b_hh, W_lin, b_lin, outp);
}